// Round 4
// baseline (122.122 us; speedup 1.0000x reference)
//
#include <hip/hip_runtime.h>
#include <math.h>

#define K_TOP   8
#define EPS_F   1e-8f
#define T_DIM   2048
#define H_DIM   1024
#define NHEADS  16

// ---------------- K1: head-mean + top-8 per row -> workspace ----------------
// One 64-lane wave per (b,t) row; 4 waves/block, no barriers, no LDS.
// Lane owns 32 elements: slot s -> element e = 256*(s>>2) + 4*lane + (s&3).
__global__ __launch_bounds__(256, 4) void ctma_topk_kernel(
    const float* __restrict__ attn,  // [B, Hh, T, T]
    float* __restrict__ ws_w,        // [rows, 8] normalized weights
    int*   __restrict__ ws_i)        // [rows, 8] indices
{
    const int lane = threadIdx.x & 63;
    const int wv_id = threadIdx.x >> 6;
    const int row = blockIdx.x * 4 + wv_id;   // b*T + t
    const int b   = row >> 11;
    const int t   = row & (T_DIM - 1);

    const float4* attn4 = reinterpret_cast<const float4*>(
        attn + (size_t)b * NHEADS * T_DIM * T_DIM + (size_t)t * T_DIM);
    const size_t hs4 = (size_t)T_DIM * T_DIM / 4;

    float acc[32];
    #pragma unroll
    for (int s = 0; s < 32; ++s) acc[s] = 0.0f;

    #pragma unroll 2
    for (int h = 0; h < NHEADS; ++h) {
        float4 tmp[8];
        #pragma unroll
        for (int j = 0; j < 8; ++j)
            tmp[j] = attn4[h * hs4 + (size_t)(lane + 64 * j)];
        #pragma unroll
        for (int j = 0; j < 8; ++j) {
            acc[4 * j + 0] += tmp[j].x;
            acc[4 * j + 1] += tmp[j].y;
            acc[4 * j + 2] += tmp[j].z;
            acc[4 * j + 3] += tmp[j].w;
        }
    }
    const float inv16 = 1.0f / (float)NHEADS;
    #pragma unroll
    for (int s = 0; s < 32; ++s) acc[s] *= inv16;

    // iterative top-8, shuffle-only, lowest-index tie-break
    float mybv = -INFINITY;
    int   mybi = 0x7fffffff;
    #pragma unroll
    for (int s = 0; s < 32; ++s) {
        if (acc[s] > mybv) { mybv = acc[s]; mybi = 256 * (s >> 2) + 4 * lane + (s & 3); }
    }
    unsigned mask = 0;

    float wvv[K_TOP];
    int   wii[K_TOP];

    for (int k = 0; k < K_TOP; ++k) {
        float bv = mybv;
        int   bi = mybi;
        #pragma unroll
        for (int off = 32; off > 0; off >>= 1) {
            const float ov = __shfl_down(bv, off);
            const int   oi = __shfl_down(bi, off);
            if (ov > bv || (ov == bv && oi < bi)) { bv = ov; bi = oi; }
        }
        bv = __shfl(bv, 0);
        bi = __shfl(bi, 0);
        wvv[k] = bv;
        wii[k] = bi;
        if (lane == ((bi >> 2) & 63)) {
            mask |= 1u << (4 * (bi >> 8) + (bi & 3));
            mybv = -INFINITY;
            mybi = 0x7fffffff;
            #pragma unroll
            for (int s = 0; s < 32; ++s) {
                const float val = ((mask >> s) & 1u) ? -INFINITY : acc[s];
                if (val > mybv) { mybv = val; mybi = 256 * (s >> 2) + 4 * lane + (s & 3); }
            }
        }
    }

    // normalize and write 8 weights + 8 indices (lanes 0..7)
    float wsum = 0.0f;
    #pragma unroll
    for (int k = 0; k < K_TOP; ++k) wsum += wvv[k];
    wsum = fmaxf(wsum, EPS_F);
    const float invs = 1.0f / wsum;

    if (lane < K_TOP) {
        ws_w[(size_t)row * K_TOP + lane] = wvv[lane] * invs;
        ws_i[(size_t)row * K_TOP + lane] = wii[lane];
    }
}

// ---------------- K2: weighted gather ----------------
// One 256-thread block per row; thread tid handles float4 #tid of H (H/4=256).
__global__ __launch_bounds__(256, 4) void ctma_gather_kernel(
    const float* __restrict__ mlp,   // [B, T, H]
    const float* __restrict__ ws_w,
    const int*   __restrict__ ws_i,
    float* __restrict__ out)         // [B, T, H]
{
    const int tid = threadIdx.x;
    const int row = blockIdx.x;
    const int b   = row >> 11;

    float w[K_TOP];
    int   gi[K_TOP];
    #pragma unroll
    for (int k = 0; k < K_TOP; ++k) {
        w[k]  = ws_w[(size_t)row * K_TOP + k];
        gi[k] = ws_i[(size_t)row * K_TOP + k];
    }

    const float4* mlp4 = reinterpret_cast<const float4*>(mlp)
                       + (size_t)b * T_DIM * (H_DIM / 4);
    float4 m[K_TOP];
    #pragma unroll
    for (int k = 0; k < K_TOP; ++k)
        m[k] = mlp4[(size_t)gi[k] * (H_DIM / 4) + tid];

    float4 o = make_float4(0.f, 0.f, 0.f, 0.f);
    #pragma unroll
    for (int k = 0; k < K_TOP; ++k) {
        o.x += w[k] * m[k].x; o.y += w[k] * m[k].y;
        o.z += w[k] * m[k].z; o.w += w[k] * m[k].w;
    }
    reinterpret_cast<float4*>(out)[(size_t)row * (H_DIM / 4) + tid] = o;
}

extern "C" void kernel_launch(void* const* d_in, const int* in_sizes, int n_in,
                              void* d_out, int out_size, void* d_ws, size_t ws_size,
                              hipStream_t stream) {
    const float* mlp  = (const float*)d_in[0];   // [B, T, H] fp32
    const float* attn = (const float*)d_in[1];   // [B, Hh, T, T] fp32
    float* out = (float*)d_out;                  // [B, T, H] fp32

    const int B = in_sizes[0] / (T_DIM * H_DIM); // = 2
    const int rows = B * T_DIM;                  // 4096

    float* ws_w = (float*)d_ws;                  // rows*8 floats
    int*   ws_i = (int*)(ws_w + (size_t)rows * K_TOP);  // rows*8 ints (total 256 KB)

    ctma_topk_kernel<<<rows / 4, 256, 0, stream>>>(attn, ws_w, ws_i);
    ctma_gather_kernel<<<rows, 256, 0, stream>>>(mlp, ws_w, ws_i, out);
}

// Round 6
// 114.833 us; speedup vs baseline: 1.0635x; 1.0635x over previous
//
#include <hip/hip_runtime.h>
#include <math.h>

#define K_TOP   8
#define EPS_F   1e-8f
#define T_DIM   2048
#define H_DIM   1024
#define NHEADS  16

typedef float f4 __attribute__((ext_vector_type(4)));

// One 64-lane wave per PAIR of consecutive rows (t, t+1): the two rows are
// contiguous in memory inside each head slab -> 16 KB contiguous reads per
// head jump (vs 8 KB), halving the number of concurrent DRAM streams.
// Register-only accumulation, no LDS, no barriers. attn loads are
// non-temporal (use-once) so they don't evict the mlp table from L2/L3.
__global__ __launch_bounds__(256, 2) void ctma_pair_kernel(
    const float* __restrict__ mlp,   // [B, T, H]
    const float* __restrict__ attn,  // [B, Hh, T, T]
    float* __restrict__ out)         // [B, T, H]
{
    const int lane  = threadIdx.x & 63;
    const int wv_id = threadIdx.x >> 6;
    const int pair  = blockIdx.x * 4 + wv_id;   // 0..2047
    const int row0  = pair * 2;                 // b*T + t0 (t0 even)
    const int b     = row0 >> 11;

    const f4* a4 = reinterpret_cast<const f4*>(
        attn + (size_t)b * NHEADS * T_DIM * T_DIM + (size_t)(row0 & (T_DIM - 1)) * T_DIM);
    const size_t hs4 = (size_t)T_DIM * T_DIM / 4;

    // ---------------- Phase 1: head-mean of 2 rows -> registers ----------------
    float acc[2][32];
    #pragma unroll
    for (int r = 0; r < 2; ++r)
        #pragma unroll
        for (int s = 0; s < 32; ++s) acc[r][s] = 0.0f;

    for (int h = 0; h < NHEADS; ++h) {
        f4 ta[8], tb[8];
        const f4* hp = a4 + (size_t)h * hs4;
        #pragma unroll
        for (int j = 0; j < 8; ++j)
            ta[j] = __builtin_nontemporal_load(&hp[64 * j + lane]);
        #pragma unroll
        for (int j = 0; j < 8; ++j)
            tb[j] = __builtin_nontemporal_load(&hp[512 + 64 * j + lane]);
        #pragma unroll
        for (int j = 0; j < 8; ++j) {
            acc[0][4*j+0] += ta[j].x; acc[0][4*j+1] += ta[j].y;
            acc[0][4*j+2] += ta[j].z; acc[0][4*j+3] += ta[j].w;
            acc[1][4*j+0] += tb[j].x; acc[1][4*j+1] += tb[j].y;
            acc[1][4*j+2] += tb[j].z; acc[1][4*j+3] += tb[j].w;
        }
    }
    const float inv16 = 1.0f / (float)NHEADS;
    #pragma unroll
    for (int r = 0; r < 2; ++r)
        #pragma unroll
        for (int s = 0; s < 32; ++s) acc[r][s] *= inv16;

    // ---------------- Phase 2+3: per row, top-8 + renorm + gather ----------------
    const f4* mlp4 = reinterpret_cast<const f4*>(mlp)
                   + (size_t)b * T_DIM * (H_DIM / 4);

    #pragma unroll
    for (int r = 0; r < 2; ++r) {
        // slot s -> element e = 256*(s>>2) + 4*lane + (s&3), ascending in s
        float mybv = -INFINITY;
        int   mybi = 0x7fffffff;
        #pragma unroll
        for (int s = 0; s < 32; ++s) {
            if (acc[r][s] > mybv) { mybv = acc[r][s]; mybi = 256 * (s >> 2) + 4 * lane + (s & 3); }
        }
        unsigned mask = 0;

        float wvv[K_TOP];
        int   wii[K_TOP];

        for (int k = 0; k < K_TOP; ++k) {
            float bv = mybv;
            int   bi = mybi;
            #pragma unroll
            for (int off = 32; off > 0; off >>= 1) {
                const float ov = __shfl_down(bv, off);
                const int   oi = __shfl_down(bi, off);
                if (ov > bv || (ov == bv && oi < bi)) { bv = ov; bi = oi; }
            }
            bv = __shfl(bv, 0);
            bi = __shfl(bi, 0);
            wvv[k] = bv;
            wii[k] = bi;
            if (lane == ((bi >> 2) & 63)) {
                mask |= 1u << (4 * (bi >> 8) + (bi & 3));
                mybv = -INFINITY;
                mybi = 0x7fffffff;
                #pragma unroll
                for (int s = 0; s < 32; ++s) {
                    const float val = ((mask >> s) & 1u) ? -INFINITY : acc[r][s];
                    if (val > mybv) { mybv = val; mybi = 256 * (s >> 2) + 4 * lane + (s & 3); }
                }
            }
        }

        float wsum = 0.0f;
        #pragma unroll
        for (int k = 0; k < K_TOP; ++k) wsum += wvv[k];
        wsum = fmaxf(wsum, EPS_F);
        const float invs = 1.0f / wsum;

        f4 o[4];
        #pragma unroll
        for (int j = 0; j < 4; ++j) o[j] = (f4)(0.0f);

        #pragma unroll
        for (int k = 0; k < K_TOP; ++k) {
            const float w = wvv[k] * invs;
            const f4* src = mlp4 + (size_t)wii[k] * (H_DIM / 4);
            #pragma unroll
            for (int j = 0; j < 4; ++j) {
                const f4 m = src[lane + 64 * j];
                o[j] += w * m;
            }
        }

        f4* out4 = reinterpret_cast<f4*>(out) + (size_t)(row0 + r) * (H_DIM / 4);
        #pragma unroll
        for (int j = 0; j < 4; ++j)
            __builtin_nontemporal_store(o[j], &out4[lane + 64 * j]);
    }
}

extern "C" void kernel_launch(void* const* d_in, const int* in_sizes, int n_in,
                              void* d_out, int out_size, void* d_ws, size_t ws_size,
                              hipStream_t stream) {
    const float* mlp  = (const float*)d_in[0];   // [B, T, H] fp32
    const float* attn = (const float*)d_in[1];   // [B, Hh, T, T] fp32
    float* out = (float*)d_out;                  // [B, T, H] fp32

    const int B = in_sizes[0] / (T_DIM * H_DIM); // = 2
    const int pairs = B * T_DIM / 2;             // 2048
    const int nblocks = pairs / 4;               // 512 blocks x 4 waves

    ctma_pair_kernel<<<nblocks, 256, 0, stream>>>(mlp, attn, out);
}